// Round 6
// baseline (87.045 us; speedup 1.0000x reference)
//
#include <hip/hip_runtime.h>
#include <hip/hip_bf16.h>

typedef __bf16 bf16;
typedef __attribute__((ext_vector_type(8))) __bf16 bf16x8;
typedef __attribute__((ext_vector_type(4))) float floatx4;

#define PP 16
#define PPW 9
#define CFEAT 432      // C*P*PW = 3*16*9
#define EDIM 768
#define KDIM 768       // C*P*P = 3*256
#define NPAT 196
#define NBATCH 128
#define MROWS (NBATCH * NPAT)  // 25088

// prep_kernel block ranges
#define NB_W 2304                 // build_w: 768*3
#define NB_CLS 384                // cls: 128*768/256
#define NB_UNF 9408               // unfold: 25088*768/8/256
#define NB_PREP (NB_W + NB_CLS + NB_UNF)

__device__ inline void gload16(const void* g, void* l) {
  __builtin_amdgcn_global_load_lds(
      (const __attribute__((address_space(1))) void*)g,
      (__attribute__((address_space(3))) void*)l, 16, 0, 0);
}

// ---------------------------------------------------------------------------
// Kernel 1 (merged prep): build W_eff; cls row; patch-unfold x -> bf16 A.
// (unchanged from round 5 — proven)
// ---------------------------------------------------------------------------
__global__ __launch_bounds__(256) void prep_kernel(
    const float* __restrict__ x, const float* __restrict__ pw,
    const float* __restrict__ fwh, const float* __restrict__ fww,
    const float* __restrict__ cls, const float* __restrict__ pos,
    bf16* __restrict__ Wb, bf16* __restrict__ A, float* __restrict__ out) {
  const int blk = blockIdx.x;
  const int t = threadIdx.x;

  if (blk >= NB_W + NB_CLS) {  // ---- unfold (bulk path) ----
    const int i = (blk - NB_W - NB_CLS) * 256 + t;  // < 2408448
    const int w8 = i % 28;
    const int tmp = i / 28;
    const int h = tmp % 224;
    const int tmp2 = tmp / 224;
    const int c = tmp2 % 3;
    const int b = tmp2 / 3;
    const float4 f0 = *reinterpret_cast<const float4*>(x + (size_t)i * 8);
    const float4 f1 = *reinterpret_cast<const float4*>(x + (size_t)i * 8 + 4);
    bf16x8 v;
    v[0] = (bf16)f0.x; v[1] = (bf16)f0.y; v[2] = (bf16)f0.z; v[3] = (bf16)f0.w;
    v[4] = (bf16)f1.x; v[5] = (bf16)f1.y; v[6] = (bf16)f1.z; v[7] = (bf16)f1.w;
    const int row = b * NPAT + (h >> 4) * 14 + (w8 >> 1);
    const int k = c * 256 + (h & 15) * 16 + (w8 & 1) * 8;
    *reinterpret_cast<bf16x8*>(A + (size_t)row * KDIM + k) = v;
  } else if (blk < NB_W) {  // ---- build W_eff ----
    __shared__ float s_pw[144];
    __shared__ float s_fh[16];
    __shared__ float s_fw[9];
    __shared__ float s_cos[16];
    const int e = blk / 3;
    const int c = blk % 3;
    if (t < 144) s_pw[t] = pw[e * CFEAT + c * 144 + t];
    if (t < 16) {
      s_fh[t] = fwh[t];
      s_cos[t] = cosf((float)t * 0.39269908169872414f);  // 2*pi/16
    }
    if (t < 9) s_fw[t] = fww[t];
    __syncthreads();
    const int h = t >> 4, w = t & 15;
    float acc = 0.f;
#pragma unroll
    for (int u = 0; u < 16; ++u) {
      const float fh = s_fh[u];
      const int uh = (u * h) & 15;
#pragma unroll
      for (int v = 0; v < 9; ++v) {
        acc += s_pw[u * 9 + v] * s_fw[v] * s_cos[(uh + v * w) & 15] * fh;
      }
    }
    Wb[e * KDIM + c * 256 + t] = (bf16)(acc * 0.0625f);
  } else {  // ---- cls row ----
    const int idx = (blk - NB_W) * 256 + t;  // < 128*768
    const int b = idx / 768;
    const int e = idx - b * 768;
    out[(size_t)b * 197 * 768 + e] = cls[e] + pos[e];
  }
}

// ---------------------------------------------------------------------------
// Kernel 2: phase-pipelined GEMM (T3+T4 counted-vmcnt schedule, T2 swizzle,
// T5 setprio, T1 bijective XCD swizzle).
// BM=256, BN=128, BK=64, 8 waves (4M x 2N), per-wave 64x64 output.
// LDS: A 2buf x 2ksub x [256x32] (64KB) + B 2buf x 2ksub x [128x32] (32KB).
// Per K-tile: 2 phases (ksub 0/1); each phase: 8 ds_read_b128 -> issue 3
// gload_lds (one future half-tile group) -> s_barrier -> 16 MFMA (setprio) ->
// s_waitcnt vmcnt(6) -> s_barrier.  Loads are never drained to 0 in-loop.
// Stage schedule (derived, clobber-safe by issue order after barriers):
//   tile kt ph0: stage (buf (kt+1)&1, ksub1) <- K-tile kt+1
//   tile kt ph1: stage (buf (kt+2)&1, ksub0) <- K-tile kt+2
// vmcnt(6): 3 loads/phase, allow 2 phases outstanding, older must have landed.
// LDS XOR swizzle (both-sides, rule 21): chunk q ^= (row ^ (row>>2)) & 3,
// applied to the per-lane GLOBAL source address (gload_lds dest is linear)
// and to the ds_read address -> conflict-free b128 reads.
// ---------------------------------------------------------------------------
__global__ __launch_bounds__(512) void gemm_8ph_kernel(
    const bf16* __restrict__ A, const bf16* __restrict__ Wb,
    const float* __restrict__ pb, const float* __restrict__ pos,
    float* __restrict__ out) {
  __shared__ __align__(16) bf16 sA[2 * 2 * 8192];  // [buf][ksub][256*32]
  __shared__ __align__(16) bf16 sB[2 * 2 * 4096];  // [buf][ksub][128*32]

  const int bid = blockIdx.x;  // 0..587 ; 588 = 8*73 + 4 -> m204 bijective
  const int xcd = bid & 7;
  const int idx = bid >> 3;
  const int wgid = (xcd < 4 ? xcd * 74 : 296 + (xcd - 4) * 73) + idx;
  const int mt = wgid / 6;       // 0..97
  const int nt = wgid - mt * 6;  // 0..5

  const int t = threadIdx.x;
  const int l = t & 63;
  const int wv = t >> 6;         // 0..7
  const int wm = wv >> 1;        // 0..3 (64-row group)
  const int wn = wv & 1;         // 0..1 (64-col group)
  const int lr = l & 15, lq = l >> 4;

  // ---- staging precompute (per-lane global src, pre-swizzled) ----
  // A: chunks c = j*512 + t, j=0,1 ; row=c>>2 (0..255), q=c&3
  const int ra0 = t >> 2, ra1 = (512 + t) >> 2;
  const int qa0 = (t & 3) ^ ((ra0 ^ (ra0 >> 2)) & 3);
  const int qa1 = (t & 3) ^ ((ra1 ^ (ra1 >> 2)) & 3);
  const bf16* gA0 = A + (size_t)(mt * 256 + ra0) * KDIM + qa0 * 8;
  const bf16* gA1 = A + (size_t)(mt * 256 + ra1) * KDIM + qa1 * 8;
  // B: chunk c = t ; row=c>>2 (0..127)
  const int rb0 = t >> 2;
  const int qb0 = (t & 3) ^ ((rb0 ^ (rb0 >> 2)) & 3);
  const bf16* gB0 = Wb + (size_t)(nt * 128 + rb0) * KDIM + qb0 * 8;

#define SLOTA(b, s) (sA + ((b)*2 + (s)) * 8192)
#define SLOTB(b, s) (sB + ((b)*2 + (s)) * 4096)

  // one half-tile group = A(16KB, 2 loads) + B(8KB, 1 load) : 3 loads/thread
#define STAGE(b, s, kts)                                   \
  do {                                                     \
    const int ko = (kts)*64 + (s)*32;                      \
    gload16(gA0 + ko, SLOTA(b, s) + wv * 512);             \
    gload16(gA1 + ko, SLOTA(b, s) + 4096 + wv * 512);      \
    gload16(gB0 + ko, SLOTB(b, s) + wv * 512);             \
  } while (0)

  floatx4 acc[4][4];
#pragma unroll
  for (int i = 0; i < 4; ++i)
#pragma unroll
    for (int j = 0; j < 4; ++j) acc[i][j] = (floatx4){0.f, 0.f, 0.f, 0.f};

#define PHASE(b, s, sb, ss, skt)                                        \
  do {                                                                  \
    bf16x8 af[4], bfr[4];                                               \
    _Pragma("unroll") for (int mf = 0; mf < 4; ++mf) {                  \
      const int r = wm * 64 + mf * 16 + lr;                             \
      const int qp = lq ^ ((r ^ (r >> 2)) & 3);                         \
      af[mf] = *reinterpret_cast<const bf16x8*>(SLOTA(b, s) + r * 32 +  \
                                                qp * 8);                \
    }                                                                   \
    _Pragma("unroll") for (int nf = 0; nf < 4; ++nf) {                  \
      const int r = wn * 64 + nf * 16 + lr;                             \
      const int qp = lq ^ ((r ^ (r >> 2)) & 3);                         \
      bfr[nf] = *reinterpret_cast<const bf16x8*>(SLOTB(b, s) + r * 32 + \
                                                 qp * 8);               \
    }                                                                   \
    STAGE(sb, ss, skt);                                                 \
    asm volatile("" ::: "memory");                                      \
    __builtin_amdgcn_s_barrier();                                       \
    __builtin_amdgcn_s_setprio(1);                                      \
    _Pragma("unroll") for (int mf = 0; mf < 4; ++mf)                    \
        _Pragma("unroll") for (int nf = 0; nf < 4; ++nf) acc[mf][nf] =  \
            __builtin_amdgcn_mfma_f32_16x16x32_bf16(af[mf], bfr[nf],    \
                                                    acc[mf][nf], 0, 0,  \
                                                    0);                 \
    __builtin_amdgcn_s_setprio(0);                                      \
    asm volatile("s_waitcnt vmcnt(6)" ::: "memory");                    \
    __builtin_amdgcn_s_barrier();                                       \
  } while (0)

  // prologue: 3 half-tile groups (9 loads); vmcnt(6) -> first group landed
  STAGE(0, 0, 0);
  STAGE(0, 1, 0);
  STAGE(1, 0, 1);
  asm volatile("s_waitcnt vmcnt(6)" ::: "memory");
  __builtin_amdgcn_s_barrier();

  // main loop: 12 K-tiles, 2 per unrolled body (static buf parity)
#define TILE(B, KT)                                  \
  do {                                               \
    const int k1 = (KT) + 1 < 12 ? (KT) + 1 : 11;    \
    const int k2 = (KT) + 2 < 12 ? (KT) + 2 : 11;    \
    PHASE(B, 0, (B) ^ 1, 1, k1);                     \
    PHASE(B, 1, (B), 0, k2);                         \
  } while (0)

  for (int kt2 = 0; kt2 < 12; kt2 += 2) {
    TILE(0, kt2);
    TILE(1, kt2 + 1);
  }
#undef TILE
#undef PHASE
#undef STAGE
#undef SLOTA
#undef SLOTB

  // epilogue: out[b][1+n][e] = acc + proj_b[e] + pos_emb[1+n][e]
  float pbv[4];
#pragma unroll
  for (int ni = 0; ni < 4; ++ni)
    pbv[ni] = pb[nt * 128 + wn * 64 + ni * 16 + lr];

#pragma unroll
  for (int mi = 0; mi < 4; ++mi) {
#pragma unroll
    for (int j = 0; j < 4; ++j) {
      const unsigned m = wm * 64 + mi * 16 + lq * 4 + j;
      const unsigned Rr = mt * 256u + m;
      const unsigned b2 = Rr / 196u;
      const unsigned np2 = Rr - b2 * 196u;
      float* orow = out + ((size_t)b2 * 197 + 1 + np2) * 768;
      const float* prow = pos + (size_t)(1 + np2) * 768;
#pragma unroll
      for (int ni = 0; ni < 4; ++ni) {
        const int e = nt * 128 + wn * 64 + ni * 16 + lr;
        orow[e] = acc[mi][ni][j] + pbv[ni] + prow[e];
      }
    }
  }
}

extern "C" void kernel_launch(void* const* d_in, const int* in_sizes, int n_in,
                              void* d_out, int out_size, void* d_ws,
                              size_t ws_size, hipStream_t stream) {
  const float* x = (const float*)d_in[0];
  const float* fwh = (const float*)d_in[1];
  const float* fww = (const float*)d_in[2];
  const float* proj_w = (const float*)d_in[3];
  const float* proj_b = (const float*)d_in[4];
  const float* cls = (const float*)d_in[5];
  const float* pos = (const float*)d_in[6];
  float* out = (float*)d_out;

  const size_t needW = (size_t)EDIM * KDIM * sizeof(bf16);  // 1.18 MB
  bf16* Wb = (bf16*)d_ws;
  bf16* A = (bf16*)((char*)d_ws + needW);  // 38.5 MB

  prep_kernel<<<NB_PREP, 256, 0, stream>>>(x, proj_w, fwh, fww, cls, pos, Wb,
                                           A, out);
  gemm_8ph_kernel<<<588, 512, 0, stream>>>(A, Wb, proj_b, pos, out);
}

// Round 8
// 82.270 us; speedup vs baseline: 1.0580x; 1.0580x over previous
//
#include <hip/hip_runtime.h>
#include <hip/hip_bf16.h>

typedef __bf16 bf16;
typedef __attribute__((ext_vector_type(8))) __bf16 bf16x8;
typedef __attribute__((ext_vector_type(4))) float floatx4;

#define PP 16
#define PPW 9
#define CFEAT 432      // C*P*PW = 3*16*9
#define EDIM 768
#define KDIM 768       // C*P*P = 3*256
#define NPAT 196
#define NBATCH 128
#define MROWS (NBATCH * NPAT)  // 25088

// prep_kernel block ranges
#define NB_W 2304                 // build_w: 768*3
#define NB_CLS 384                // cls: 128*768/256
#define NB_UNF 9408               // unfold: 25088*768/8/256
#define NB_PREP (NB_W + NB_CLS + NB_UNF)

__device__ inline void gload16(const void* g, void* l) {
  __builtin_amdgcn_global_load_lds(
      (const __attribute__((address_space(1))) void*)g,
      (__attribute__((address_space(3))) void*)l, 16, 0, 0);
}

// ---------------------------------------------------------------------------
// Kernel 1 (merged prep): build W_eff; cls row; patch-unfold x -> bf16 A.
// (unchanged — proven rounds 5/6)
// ---------------------------------------------------------------------------
__global__ __launch_bounds__(256) void prep_kernel(
    const float* __restrict__ x, const float* __restrict__ pw,
    const float* __restrict__ fwh, const float* __restrict__ fww,
    const float* __restrict__ cls, const float* __restrict__ pos,
    bf16* __restrict__ Wb, bf16* __restrict__ A, float* __restrict__ out) {
  const int blk = blockIdx.x;
  const int t = threadIdx.x;

  if (blk >= NB_W + NB_CLS) {  // ---- unfold (bulk path) ----
    const int i = (blk - NB_W - NB_CLS) * 256 + t;  // < 2408448
    const int w8 = i % 28;
    const int tmp = i / 28;
    const int h = tmp % 224;
    const int tmp2 = tmp / 224;
    const int c = tmp2 % 3;
    const int b = tmp2 / 3;
    const float4 f0 = *reinterpret_cast<const float4*>(x + (size_t)i * 8);
    const float4 f1 = *reinterpret_cast<const float4*>(x + (size_t)i * 8 + 4);
    bf16x8 v;
    v[0] = (bf16)f0.x; v[1] = (bf16)f0.y; v[2] = (bf16)f0.z; v[3] = (bf16)f0.w;
    v[4] = (bf16)f1.x; v[5] = (bf16)f1.y; v[6] = (bf16)f1.z; v[7] = (bf16)f1.w;
    const int row = b * NPAT + (h >> 4) * 14 + (w8 >> 1);
    const int k = c * 256 + (h & 15) * 16 + (w8 & 1) * 8;
    *reinterpret_cast<bf16x8*>(A + (size_t)row * KDIM + k) = v;
  } else if (blk < NB_W) {  // ---- build W_eff ----
    __shared__ float s_pw[144];
    __shared__ float s_fh[16];
    __shared__ float s_fw[9];
    __shared__ float s_cos[16];
    const int e = blk / 3;
    const int c = blk % 3;
    if (t < 144) s_pw[t] = pw[e * CFEAT + c * 144 + t];
    if (t < 16) {
      s_fh[t] = fwh[t];
      s_cos[t] = cosf((float)t * 0.39269908169872414f);  // 2*pi/16
    }
    if (t < 9) s_fw[t] = fww[t];
    __syncthreads();
    const int h = t >> 4, w = t & 15;
    float acc = 0.f;
#pragma unroll
    for (int u = 0; u < 16; ++u) {
      const float fh = s_fh[u];
      const int uh = (u * h) & 15;
#pragma unroll
      for (int v = 0; v < 9; ++v) {
        acc += s_pw[u * 9 + v] * s_fw[v] * s_cos[(uh + v * w) & 15] * fh;
      }
    }
    Wb[e * KDIM + c * 256 + t] = (bf16)(acc * 0.0625f);
  } else {  // ---- cls row ----
    const int idx = (blk - NB_W) * 256 + t;  // < 128*768
    const int b = idx / 768;
    const int e = idx - b * 768;
    out[(size_t)b * 197 * 768 + e] = cls[e] + pos[e];
  }
}

// ---------------------------------------------------------------------------
// Kernel 2: 256x128-tile GEMM, 8 waves (4M x 2N, 64x64 each), BK=32,
// double-buffered LDS (48KB -> 3 blocks/CU, up to 24 waves/CU), r5's proven
// sync discipline: STAGE(next) -> COMPUTE(cur) -> __syncthreads() (full
// fence; no raw barriers / manual vmcnt — r7's race class eliminated).
// Staging: 3 x global_load_lds width-16 per thread (512 threads: A 16KB in 2,
// B 8KB in 1).  Grid 588 = 98 mt x 6 nt with m204 bijective XCD swizzle
// (588 % 8 != 0): all 6 nt-blocks of an A-panel on one XCD (FETCH ~33MB, r5).
// Whole grid co-resident (588 < 3*256) — no dispatch rounds.
// ---------------------------------------------------------------------------
__global__ __launch_bounds__(512) void gemm_256_kernel(
    const bf16* __restrict__ A, const bf16* __restrict__ Wb,
    const float* __restrict__ pb, const float* __restrict__ pos,
    float* __restrict__ out) {
  __shared__ __align__(16) bf16 sA[2][256 * 32];  // 32 KB
  __shared__ __align__(16) bf16 sB[2][128 * 32];  // 16 KB

  const int bid = blockIdx.x;  // 0..587 ; 588 = 8*73+4 -> m204 bijective
  const int xcd = bid & 7;
  const int idx = bid >> 3;
  const int wgid = (xcd < 4 ? xcd * 74 : 296 + (xcd - 4) * 73) + idx;
  const int mt = wgid / 6;       // 0..97
  const int nt = wgid - mt * 6;  // 0..5

  const int t = threadIdx.x;
  const int l = t & 63;
  const int wv = t >> 6;   // 0..7
  const int wm = wv >> 1;  // 0..3
  const int wn = wv & 1;   // 0..1
  const int lr = l & 15, lq = l >> 4;

  // staging: thread t -> row t>>2, k-chunk (t&3)*8 ; LDS linear (elem t*8)
  const bf16* gA0 = A + (size_t)(mt * 256 + (t >> 2)) * KDIM + (t & 3) * 8;
  const bf16* gA1 = A + (size_t)(mt * 256 + 128 + (t >> 2)) * KDIM + (t & 3) * 8;
  const bf16* gB0 = Wb + (size_t)(nt * 128 + (t >> 2)) * KDIM + (t & 3) * 8;
  const int lbase = wv * 512;  // wave-uniform LDS base (elems); HW adds l*16B

#define STAGE(buf, kts)                           \
  do {                                            \
    const int ko = (kts)*32;                      \
    gload16(gA0 + ko, &sA[buf][lbase]);           \
    gload16(gA1 + ko, &sA[buf][4096 + lbase]);    \
    gload16(gB0 + ko, &sB[buf][lbase]);           \
  } while (0)

  floatx4 acc[4][4];
#pragma unroll
  for (int i = 0; i < 4; ++i)
#pragma unroll
    for (int j = 0; j < 4; ++j) acc[i][j] = (floatx4){0.f, 0.f, 0.f, 0.f};

#define COMPUTE(buf)                                                        \
  do {                                                                      \
    bf16x8 af[4], bfr[4];                                                   \
    _Pragma("unroll") for (int mi = 0; mi < 4; ++mi) {                      \
      const int r = wm * 64 + mi * 16 + lr;                                 \
      af[mi] = *reinterpret_cast<const bf16x8*>(&sA[buf][r * 32 + lq * 8]); \
    }                                                                       \
    _Pragma("unroll") for (int ni = 0; ni < 4; ++ni) {                      \
      const int r = wn * 64 + ni * 16 + lr;                                 \
      bfr[ni] = *reinterpret_cast<const bf16x8*>(&sB[buf][r * 32 + lq * 8]);\
    }                                                                       \
    _Pragma("unroll") for (int mi = 0; mi < 4; ++mi)                        \
        _Pragma("unroll") for (int ni = 0; ni < 4; ++ni) acc[mi][ni] =      \
            __builtin_amdgcn_mfma_f32_16x16x32_bf16(af[mi], bfr[ni],        \
                                                    acc[mi][ni], 0, 0, 0);  \
  } while (0)

  STAGE(0, 0);
  __syncthreads();
  int cur = 0;
  for (int kt = 0; kt < 23; ++kt) {
    STAGE(cur ^ 1, kt + 1);  // prefetch next tile (in flight thru compute)
    COMPUTE(cur);
    __syncthreads();  // full drain (vmcnt+lgkm) AFTER compute — r5 discipline
    cur ^= 1;
  }
  COMPUTE(cur);
#undef STAGE
#undef COMPUTE

  // epilogue: out[b][1+n][e] = acc + proj_b[e] + pos_emb[1+n][e]
  float pbv[4];
#pragma unroll
  for (int ni = 0; ni < 4; ++ni)
    pbv[ni] = pb[nt * 128 + wn * 64 + ni * 16 + lr];

#pragma unroll
  for (int mi = 0; mi < 4; ++mi) {
#pragma unroll
    for (int j = 0; j < 4; ++j) {
      const unsigned m = wm * 64 + mi * 16 + lq * 4 + j;
      const unsigned Rr = mt * 256u + m;
      const unsigned b2 = Rr / 196u;
      const unsigned np2 = Rr - b2 * 196u;
      float* orow = out + ((size_t)b2 * 197 + 1 + np2) * 768;
      const float* prow = pos + (size_t)(1 + np2) * 768;
#pragma unroll
      for (int ni = 0; ni < 4; ++ni) {
        const int e = nt * 128 + wn * 64 + ni * 16 + lr;
        orow[e] = acc[mi][ni][j] + pbv[ni] + prow[e];
      }
    }
  }
}

extern "C" void kernel_launch(void* const* d_in, const int* in_sizes, int n_in,
                              void* d_out, int out_size, void* d_ws,
                              size_t ws_size, hipStream_t stream) {
  const float* x = (const float*)d_in[0];
  const float* fwh = (const float*)d_in[1];
  const float* fww = (const float*)d_in[2];
  const float* proj_w = (const float*)d_in[3];
  const float* proj_b = (const float*)d_in[4];
  const float* cls = (const float*)d_in[5];
  const float* pos = (const float*)d_in[6];
  float* out = (float*)d_out;

  const size_t needW = (size_t)EDIM * KDIM * sizeof(bf16);  // 1.18 MB
  bf16* Wb = (bf16*)d_ws;
  bf16* A = (bf16*)((char*)d_ws + needW);  // 38.5 MB

  prep_kernel<<<NB_PREP, 256, 0, stream>>>(x, proj_w, fwh, fww, cls, pos, Wb,
                                           A, out);
  gemm_256_kernel<<<588, 512, 0, stream>>>(A, Wb, proj_b, pos, out);
}

// Round 9
// 81.890 us; speedup vs baseline: 1.0630x; 1.0046x over previous
//
#include <hip/hip_runtime.h>
#include <hip/hip_bf16.h>

typedef __bf16 bf16;
typedef __attribute__((ext_vector_type(8))) __bf16 bf16x8;
typedef __attribute__((ext_vector_type(4))) float floatx4;

#define PP 16
#define PPW 9
#define CFEAT 432      // C*P*PW = 3*16*9
#define EDIM 768
#define KDIM 768       // C*P*P = 3*256
#define NPAT 196
#define NBATCH 128
#define MROWS (NBATCH * NPAT)  // 25088

// prep_kernel block ranges
#define NB_W 2304                 // build_w: 768*3
#define NB_CLS 384                // cls: 128*768/256
#define NB_UNF 9408               // unfold: 25088*768/8/256
#define NB_PREP (NB_W + NB_CLS + NB_UNF)

__device__ inline void gload16(const void* g, void* l) {
  __builtin_amdgcn_global_load_lds(
      (const __attribute__((address_space(1))) void*)g,
      (__attribute__((address_space(3))) void*)l, 16, 0, 0);
}

// ---------------------------------------------------------------------------
// Kernel 1 (merged prep): build W_eff; cls row; patch-unfold x -> bf16 A.
// (unchanged — proven rounds 5/6/8)
// ---------------------------------------------------------------------------
__global__ __launch_bounds__(256) void prep_kernel(
    const float* __restrict__ x, const float* __restrict__ pw,
    const float* __restrict__ fwh, const float* __restrict__ fww,
    const float* __restrict__ cls, const float* __restrict__ pos,
    bf16* __restrict__ Wb, bf16* __restrict__ A, float* __restrict__ out) {
  const int blk = blockIdx.x;
  const int t = threadIdx.x;

  if (blk >= NB_W + NB_CLS) {  // ---- unfold (bulk path) ----
    const int i = (blk - NB_W - NB_CLS) * 256 + t;  // < 2408448
    const int w8 = i % 28;
    const int tmp = i / 28;
    const int h = tmp % 224;
    const int tmp2 = tmp / 224;
    const int c = tmp2 % 3;
    const int b = tmp2 / 3;
    const float4 f0 = *reinterpret_cast<const float4*>(x + (size_t)i * 8);
    const float4 f1 = *reinterpret_cast<const float4*>(x + (size_t)i * 8 + 4);
    bf16x8 v;
    v[0] = (bf16)f0.x; v[1] = (bf16)f0.y; v[2] = (bf16)f0.z; v[3] = (bf16)f0.w;
    v[4] = (bf16)f1.x; v[5] = (bf16)f1.y; v[6] = (bf16)f1.z; v[7] = (bf16)f1.w;
    const int row = b * NPAT + (h >> 4) * 14 + (w8 >> 1);
    const int k = c * 256 + (h & 15) * 16 + (w8 & 1) * 8;
    *reinterpret_cast<bf16x8*>(A + (size_t)row * KDIM + k) = v;
  } else if (blk < NB_W) {  // ---- build W_eff ----
    __shared__ float s_pw[144];
    __shared__ float s_fh[16];
    __shared__ float s_fw[9];
    __shared__ float s_cos[16];
    const int e = blk / 3;
    const int c = blk % 3;
    if (t < 144) s_pw[t] = pw[e * CFEAT + c * 144 + t];
    if (t < 16) {
      s_fh[t] = fwh[t];
      s_cos[t] = cosf((float)t * 0.39269908169872414f);  // 2*pi/16
    }
    if (t < 9) s_fw[t] = fww[t];
    __syncthreads();
    const int h = t >> 4, w = t & 15;
    float acc = 0.f;
#pragma unroll
    for (int u = 0; u < 16; ++u) {
      const float fh = s_fh[u];
      const int uh = (u * h) & 15;
#pragma unroll
      for (int v = 0; v < 9; ++v) {
        acc += s_pw[u * 9 + v] * s_fw[v] * s_cos[(uh + v * w) & 15] * fh;
      }
    }
    Wb[e * KDIM + c * 256 + t] = (bf16)(acc * 0.0625f);
  } else {  // ---- cls row ----
    const int idx = (blk - NB_W) * 256 + t;  // < 128*768
    const int b = idx / 768;
    const int e = idx - b * 768;
    out[(size_t)b * 197 * 768 + e] = cls[e] + pos[e];
  }
}

// ---------------------------------------------------------------------------
// Kernel 2: r5's winning GEMM (128x128 tile, 4 waves 64x64, BK=32, dbuf,
// STAGE(next)->COMPUTE(cur)->__syncthreads, XCD swizzle 147x8) with ONE
// change: LDS XOR chunk-swizzle (T2, rule 21 both-sides) to kill the 4-way
// bank conflict on ds_read_b128.
//   content map: LDS (row r, slot q) holds global k-chunk q ^ s(r),
//   s(r) = (r ^ (r>>2)) & 3, via pre-swizzled GLOBAL source address
//   (gload_lds dest stays linear); reads address slot lq ^ s(r).
//   Bank check (8-lane phase, rows r0..r0+7): even-row bank-starts become
//   {s(r)} * 4 = {0,2,1,3} * 4 -> all distinct -> conflict-free.
// ---------------------------------------------------------------------------
__global__ __launch_bounds__(256) void gemm_db_kernel(
    const bf16* __restrict__ A, const bf16* __restrict__ Wb,
    const float* __restrict__ pb, const float* __restrict__ pos,
    float* __restrict__ out) {
  __shared__ __align__(16) bf16 sA[2][128 * 32];
  __shared__ __align__(16) bf16 sB[2][128 * 32];

  const int bid = blockIdx.x;                    // 0..1175
  const int swz = (bid & 7) * 147 + (bid >> 3);  // XCD-chunked, bijective
  const int mt = swz / 6;                        // 0..195
  const int nt = swz - mt * 6;                   // 0..5
  const int t = threadIdx.x;
  const int l = t & 63;
  const int wv = t >> 6;
  const int wm = wv >> 1, wn = wv & 1;
  const int lr = l & 15, lq = l >> 4;

  // staging: thread t -> LDS slot (row t>>2, chunk t&3), dest linear.
  // Global chunk pre-swizzled: fetch chunk (t&3) ^ s(row) so LDS slot q
  // holds global chunk q ^ s(row).
  const int r8 = t >> 2;        // rows 0..63  (half 0)
  const int r8b = r8 + 64;      // rows 64..127 (half 1)
  const int sw0 = (r8 ^ (r8 >> 2)) & 3;
  const int sw1 = (r8b ^ (r8b >> 2)) & 3;
  const bf16* gA0 = A + (size_t)(mt * 128 + r8) * KDIM + (((t & 3) ^ sw0) * 8);
  const bf16* gA1 = A + (size_t)(mt * 128 + r8b) * KDIM + (((t & 3) ^ sw1) * 8);
  const bf16* gB0 = Wb + (size_t)(nt * 128 + r8) * KDIM + (((t & 3) ^ sw0) * 8);
  const bf16* gB1 = Wb + (size_t)(nt * 128 + r8b) * KDIM + (((t & 3) ^ sw1) * 8);
  const int lbase = wv * 512;  // wave-uniform LDS base (elems); HW adds l*16B

#define STAGE(buf, kts)                              \
  do {                                               \
    const int ko = (kts)*32;                         \
    gload16(gA0 + ko, &sA[buf][lbase]);              \
    gload16(gA1 + ko, &sA[buf][2048 + lbase]);       \
    gload16(gB0 + ko, &sB[buf][lbase]);              \
    gload16(gB1 + ko, &sB[buf][2048 + lbase]);       \
  } while (0)

  floatx4 acc[4][4];
#pragma unroll
  for (int i = 0; i < 4; ++i)
#pragma unroll
    for (int j = 0; j < 4; ++j) acc[i][j] = (floatx4){0.f, 0.f, 0.f, 0.f};

#define COMPUTE(buf)                                                         \
  do {                                                                       \
    bf16x8 af[4], bfr[4];                                                    \
    _Pragma("unroll") for (int mi = 0; mi < 4; ++mi) {                       \
      const int r = wm * 64 + mi * 16 + lr;                                  \
      const int qp = lq ^ ((r ^ (r >> 2)) & 3);                              \
      af[mi] = *reinterpret_cast<const bf16x8*>(&sA[buf][r * 32 + qp * 8]);  \
    }                                                                        \
    _Pragma("unroll") for (int ni = 0; ni < 4; ++ni) {                       \
      const int r = wn * 64 + ni * 16 + lr;                                  \
      const int qp = lq ^ ((r ^ (r >> 2)) & 3);                              \
      bfr[ni] = *reinterpret_cast<const bf16x8*>(&sB[buf][r * 32 + qp * 8]); \
    }                                                                        \
    _Pragma("unroll") for (int mi = 0; mi < 4; ++mi)                         \
        _Pragma("unroll") for (int ni = 0; ni < 4; ++ni) acc[mi][ni] =       \
            __builtin_amdgcn_mfma_f32_16x16x32_bf16(af[mi], bfr[ni],         \
                                                    acc[mi][ni], 0, 0, 0);   \
  } while (0)

  STAGE(0, 0);
  __syncthreads();
  int cur = 0;
  for (int kt = 0; kt < 23; ++kt) {
    STAGE(cur ^ 1, kt + 1);  // prefetch next tile (in flight thru compute)
    COMPUTE(cur);
    __syncthreads();  // vmcnt+lgkm drain AFTER compute — r5 discipline
    cur ^= 1;
  }
  COMPUTE(cur);
#undef STAGE
#undef COMPUTE

  // epilogue: out[b][1+n][e] = acc + proj_b[e] + pos_emb[1+n][e]
  float pbv[4];
#pragma unroll
  for (int ni = 0; ni < 4; ++ni)
    pbv[ni] = pb[nt * 128 + wn * 64 + ni * 16 + lr];

#pragma unroll
  for (int mi = 0; mi < 4; ++mi) {
#pragma unroll
    for (int j = 0; j < 4; ++j) {
      const unsigned m = wm * 64 + mi * 16 + lq * 4 + j;
      const unsigned Rr = mt * 128u + m;
      const unsigned b2 = Rr / 196u;
      const unsigned np2 = Rr - b2 * 196u;
      float* orow = out + ((size_t)b2 * 197 + 1 + np2) * 768;
      const float* prow = pos + (size_t)(1 + np2) * 768;
#pragma unroll
      for (int ni = 0; ni < 4; ++ni) {
        const int e = nt * 128 + wn * 64 + ni * 16 + lr;
        orow[e] = acc[mi][ni][j] + pbv[ni] + prow[e];
      }
    }
  }
}

extern "C" void kernel_launch(void* const* d_in, const int* in_sizes, int n_in,
                              void* d_out, int out_size, void* d_ws,
                              size_t ws_size, hipStream_t stream) {
  const float* x = (const float*)d_in[0];
  const float* fwh = (const float*)d_in[1];
  const float* fww = (const float*)d_in[2];
  const float* proj_w = (const float*)d_in[3];
  const float* proj_b = (const float*)d_in[4];
  const float* cls = (const float*)d_in[5];
  const float* pos = (const float*)d_in[6];
  float* out = (float*)d_out;

  const size_t needW = (size_t)EDIM * KDIM * sizeof(bf16);  // 1.18 MB
  bf16* Wb = (bf16*)d_ws;
  bf16* A = (bf16*)((char*)d_ws + needW);  // 38.5 MB

  prep_kernel<<<NB_PREP, 256, 0, stream>>>(x, proj_w, fwh, fww, cls, pos, Wb,
                                           A, out);
  gemm_db_kernel<<<1176, 256, 0, stream>>>(A, Wb, proj_b, pos, out);
}